// Round 6
// baseline (136.758 us; speedup 1.0000x reference)
//
#include <hip/hip_runtime.h>
#include <hip/hip_bf16.h>
#include <hip/hip_cooperative_groups.h>

namespace cg = cooperative_groups;

// SpeakerEmbedder: token histogram (bag-of-words mean) -> 3-layer MLP -> L2 normalize.
// B=64, T=16384, VOCAB=1024, HIDDEN=512, EMBED=256. All math in fp32.
//
// Round-6: rounds 4/5 showed per-kernel work is only ~8-10us; the remaining
// ~16us was inter-dispatch gap across 5 launches. Fuse everything into ONE
// cooperative kernel (grid=256 blocks x 256 thr, 1 block/CU) with 5 phases
// separated by grid.sync(). Dense phases keep the round-4 register-blocked
// structure (4 rows x 32 cols per block; x transposed in LDS as float4[k]).
// LDS xs4 index padded (k + (k>>6)) to break the 4-way bank aliasing between
// the 4 k-groups sharing a wave.

#define VOCAB 1024
#define HIDDEN 512
#define EMBED 256
#define TOK_T 16384
#define BATCH 64
#define HSEG 4  // histogram segments per row

#define XSIDX(k) ((k) + ((k) >> 6))  // pad: +1 float4 per 64 -> k-groups land on distinct banks

struct SMemDense {
    float4 xs4[VOCAB + VOCAB / 64];  // x transposed: [k][4 rows], padded
    float part[16][4][32];           // [kg][r][jl]
};
union SMem {
    unsigned cnt[VOCAB];
    SMemDense d;
};

// ---------------------------------------------------------------------------
// Phase: row-blocked dense. Block tile: 4 rows x 32 cols; 256 thr = 16 kg x 16 jt,
// thread tile 4 rows x 2 cols. Grid mapping: blk -> (rg = blk/JW, jw = blk%JW).
// FROM_COUNTS: input is u32 counts[64][4][VOCAB]; pooled = segsum/T on the fly.
// SSQ: also emit per-(row, jw) partial sum of squares (for the L2 norm).
// ---------------------------------------------------------------------------
template <int K, int OUT, bool RELU, bool FROM_COUNTS, bool SSQ>
__device__ __forceinline__ void dense_phase(SMem& sm, int blk,
                                            const void* __restrict__ in,
                                            const float* __restrict__ W,
                                            const float* __restrict__ bias,
                                            float* __restrict__ outp,
                                            float* __restrict__ ssq_part) {
    constexpr int KG = 16;
    constexpr int KC = K / KG;
    constexpr int JW = OUT / 32;

    const int rg = blk / JW;
    const int jw = blk % JW;
    const int b0 = rg * 4;
    const int tid = threadIdx.x;

    // ---- stage x (4 rows) transposed into LDS ----
    if constexpr (FROM_COUNTS) {
        const unsigned* __restrict__ c = (const unsigned*)in;
        const float invT = 1.0f / (float)TOK_T;
        for (int k = tid; k < K; k += 256) {
            float4 v;
#pragma unroll
            for (int r = 0; r < 4; ++r) {
                const unsigned* __restrict__ cr = c + (size_t)(b0 + r) * HSEG * VOCAB;
                unsigned s = cr[k] + cr[k + VOCAB] + cr[k + 2 * VOCAB] + cr[k + 3 * VOCAB];
                (&v.x)[r] = (float)s * invT;
            }
            sm.d.xs4[XSIDX(k)] = v;
        }
    } else {
        const float* __restrict__ x = (const float*)in;
        for (int k = tid; k < K; k += 256) {
            float4 v;
            v.x = x[(size_t)(b0 + 0) * K + k];
            v.y = x[(size_t)(b0 + 1) * K + k];
            v.z = x[(size_t)(b0 + 2) * K + k];
            v.w = x[(size_t)(b0 + 3) * K + k];
            sm.d.xs4[XSIDX(k)] = v;
        }
    }
    __syncthreads();

    // ---- compute: thread (kg, jt) -> 4 rows x 2 cols over its K-chunk ----
    const int jt = tid & 15;
    const int kg = tid >> 4;
    const float* __restrict__ w = W + (size_t)(kg * KC) * OUT + jw * 32 + jt * 2;

    float2 acc0 = {0.f, 0.f}, acc1 = {0.f, 0.f}, acc2 = {0.f, 0.f}, acc3 = {0.f, 0.f};
#pragma unroll 8
    for (int ks = 0; ks < KC; ++ks) {
        const int k = kg * KC + ks;
        const float4 xv = sm.d.xs4[XSIDX(k)];                       // bank-conflict-free bcast
        const float2 wv = *(const float2*)(w + (size_t)ks * OUT);   // coalesced global
        acc0.x = fmaf(xv.x, wv.x, acc0.x); acc0.y = fmaf(xv.x, wv.y, acc0.y);
        acc1.x = fmaf(xv.y, wv.x, acc1.x); acc1.y = fmaf(xv.y, wv.y, acc1.y);
        acc2.x = fmaf(xv.z, wv.x, acc2.x); acc2.y = fmaf(xv.z, wv.y, acc2.y);
        acc3.x = fmaf(xv.w, wv.x, acc3.x); acc3.y = fmaf(xv.w, wv.y, acc3.y);
    }

    *(float2*)&sm.d.part[kg][0][jt * 2] = acc0;
    *(float2*)&sm.d.part[kg][1][jt * 2] = acc1;
    *(float2*)&sm.d.part[kg][2][jt * 2] = acc2;
    *(float2*)&sm.d.part[kg][3][jt * 2] = acc3;
    __syncthreads();

    // ---- reduce 16 k-groups, bias, activation, store (+ optional ssq) ----
    if (tid < 128) {
        const int r = tid >> 5;   // 0..3
        const int jl = tid & 31;  // 0..31
        float s = bias[jw * 32 + jl];
#pragma unroll
        for (int g = 0; g < KG; ++g) s += sm.d.part[g][r][jl];
        if (RELU) s = fmaxf(s, 0.0f);
        outp[(size_t)(b0 + r) * OUT + jw * 32 + jl] = s;
        if constexpr (SSQ) {
            float s2 = s * s;
#pragma unroll
            for (int off = 16; off > 0; off >>= 1) s2 += __shfl_down(s2, off, 32);
            if (jl == 0) ssq_part[(size_t)(b0 + r) * JW + jw] = s2;
        }
    }
}

// ---------------------------------------------------------------------------
// The single fused cooperative kernel. Grid MUST be 256 blocks x 256 threads.
// ---------------------------------------------------------------------------
__global__ __launch_bounds__(256) void fused_kernel(const int* __restrict__ tokens,
                                                    const float* __restrict__ W1,
                                                    const float* __restrict__ b1,
                                                    const float* __restrict__ W2,
                                                    const float* __restrict__ b2,
                                                    const float* __restrict__ W3,
                                                    const float* __restrict__ b3,
                                                    float* __restrict__ out,
                                                    unsigned* __restrict__ counts,
                                                    float* __restrict__ h1,
                                                    float* __restrict__ h2,
                                                    float* __restrict__ emb,
                                                    float* __restrict__ ssq_part) {
    __shared__ SMem sm;
    cg::grid_group grid = cg::this_grid();
    const int blk = blockIdx.x;
    const int tid = threadIdx.x;

    // ===== Phase 1: partial token histograms (64 rows x 4 segments) =====
    {
#pragma unroll
        for (int i = 0; i < VOCAB / 256; ++i) sm.cnt[tid + 256 * i] = 0u;
        __syncthreads();

        const int b = blk >> 2;
        const int seg = blk & 3;
        const int4* __restrict__ t4 =
            reinterpret_cast<const int4*>(tokens + (size_t)b * TOK_T + seg * (TOK_T / HSEG));
#pragma unroll
        for (int i = 0; i < TOK_T / HSEG / 4 / 256; ++i) {  // 4 iterations
            int4 v = t4[i * 256 + tid];
            atomicAdd(&sm.cnt[v.x & (VOCAB - 1)], 1u);
            atomicAdd(&sm.cnt[v.y & (VOCAB - 1)], 1u);
            atomicAdd(&sm.cnt[v.z & (VOCAB - 1)], 1u);
            atomicAdd(&sm.cnt[v.w & (VOCAB - 1)], 1u);
        }
        __syncthreads();

        unsigned* __restrict__ row = counts + ((size_t)b * HSEG + seg) * VOCAB;
        uint4 o;
        o.x = sm.cnt[tid * 4 + 0];
        o.y = sm.cnt[tid * 4 + 1];
        o.z = sm.cnt[tid * 4 + 2];
        o.w = sm.cnt[tid * 4 + 3];
        reinterpret_cast<uint4*>(row)[tid] = o;
    }
    grid.sync();

    // ===== Phase 2: dense1 (1024 -> 512, relu), pooled fused from counts =====
    dense_phase<VOCAB, HIDDEN, true, true, false>(sm, blk, counts, W1, b1, h1, nullptr);
    grid.sync();

    // ===== Phase 3: dense2 (512 -> 512, relu) =====
    dense_phase<HIDDEN, HIDDEN, true, false, false>(sm, blk, h1, W2, b2, h2, nullptr);
    grid.sync();

    // ===== Phase 4: dense3 (512 -> 256) + partial sum-of-squares =====
    if (blk < (BATCH / 4) * (EMBED / 32)) {  // 128 active blocks
        dense_phase<HIDDEN, EMBED, false, false, true>(sm, blk, h2, W3, b3, emb, ssq_part);
    }
    grid.sync();

    // ===== Phase 5: L2 normalize (64 active blocks, one per row) =====
    if (blk < BATCH) {
        const int b = blk;
        const float v = emb[(size_t)b * EMBED + tid];
        const float* __restrict__ sp = ssq_part + (size_t)b * (EMBED / 32);
        float total = 0.0f;
#pragma unroll
        for (int i = 0; i < EMBED / 32; ++i) total += sp[i];
        out[(size_t)b * EMBED + tid] = v / fmaxf(sqrtf(total), 1e-12f);  // F.normalize eps
    }
}

// ---------------------------------------------------------------------------
// Launch
// ---------------------------------------------------------------------------
extern "C" void kernel_launch(void* const* d_in, const int* in_sizes, int n_in,
                              void* d_out, int out_size, void* d_ws, size_t ws_size,
                              hipStream_t stream) {
    const int*   tokens = (const int*)d_in[0];   // [64,16384], values in [0,1024)
    const float* W1     = (const float*)d_in[1]; // [1024,512]
    const float* b1     = (const float*)d_in[2]; // [512]
    const float* W2     = (const float*)d_in[3]; // [512,512]
    const float* b2     = (const float*)d_in[4]; // [512]
    const float* W3     = (const float*)d_in[5]; // [512,256]
    const float* b3     = (const float*)d_in[6]; // [256]
    float*       out    = (float*)d_out;         // [64,256]

    // Workspace (fully rewritten every call): ~1.35 MB.
    unsigned* counts   = (unsigned*)d_ws;                                  // [64][4][1024] u32
    float*    h1       = (float*)(counts + (size_t)BATCH * HSEG * VOCAB);  // [64][512]
    float*    h2       = h1 + (size_t)BATCH * HIDDEN;                      // [64][512]
    float*    emb      = h2 + (size_t)BATCH * HIDDEN;                      // [64][256]
    float*    ssq_part = emb + (size_t)BATCH * EMBED;                      // [64][8]

    void* args[] = {&tokens, &W1, &b1, &W2, &b2, &W3, &b3,
                    &out, &counts, &h1, &h2, &emb, &ssq_part};
    hipLaunchCooperativeKernel((const void*)fused_kernel, dim3(256), dim3(256),
                               args, 0, stream);
}

// Round 7
// 58.265 us; speedup vs baseline: 2.3471x; 2.3471x over previous
//
#include <hip/hip_runtime.h>
#include <hip/hip_bf16.h>

// SpeakerEmbedder: token histogram (bag-of-words mean) -> 3-layer MLP -> L2 normalize.
// B=64, T=16384, VOCAB=1024, HIDDEN=512, EMBED=256. All math in fp32.
//
// Round-7: single cooperative launch, but NO grid.sync (round 6 showed it costs
// ~29us/barrier: device-scope L2 wb+inv nukes the weight cache each phase).
// All cross-block deps are row-local, so we use per-rowgroup arrival flags.
// Cross-XCD data visibility WITHOUT cache flushes: every cross-phase datum
// (counts/h1/h2/emb/ssq/flags) moves via __hip_atomic_{store,load}(RELAXED,
// AGENT) -> sc0 sc1 bypass ops that hit the device coherence point directly.
// Weights are read-only and stay L2-cached the whole kernel.
// Producer protocol: atomic stores -> __syncthreads() (drains vmcnt before
// s_barrier per compiler semantics; explicit s_waitcnt added as belt+braces)
// -> thread0 fetch_add(flag). Consumer: thread0 relaxed-spin -> __syncthreads()
// -> atomic stage loads. Flags zeroed by a tiny hipMemsetAsync node (ws is
// poisoned 0xAA before timing).

#define VOCAB 1024
#define HIDDEN 512
#define EMBED 256
#define TOK_T 16384
#define BATCH 64
#define HSEG 2  // histogram segments per row (128 hist blocks)

#define AGENT __HIP_MEMORY_SCOPE_AGENT

__device__ __forceinline__ unsigned ld_u32(const unsigned* p) {
    return __hip_atomic_load(p, __ATOMIC_RELAXED, AGENT);
}
__device__ __forceinline__ float ld_f32(const float* p) {
    return __hip_atomic_load(p, __ATOMIC_RELAXED, AGENT);
}
__device__ __forceinline__ void st_u32(unsigned* p, unsigned v) {
    __hip_atomic_store(p, v, __ATOMIC_RELAXED, AGENT);
}
__device__ __forceinline__ void st_f32(float* p, float v) {
    __hip_atomic_store(p, v, __ATOMIC_RELAXED, AGENT);
}

// All threads of the block arrive; thread0 publishes one arrival on flag.
__device__ __forceinline__ void signal(unsigned* flag) {
    asm volatile("s_waitcnt vmcnt(0)" ::: "memory");  // our stores acked at coherence point
    __syncthreads();                                  // all waves' stores drained
    if (threadIdx.x == 0) __hip_atomic_fetch_add(flag, 1u, __ATOMIC_RELAXED, AGENT);
}

__device__ __forceinline__ void wait_one(const unsigned* flag, unsigned target) {
    while (__hip_atomic_load(flag, __ATOMIC_RELAXED, AGENT) != target)
        __builtin_amdgcn_s_sleep(1);
}

#define XSIDX(k) ((k) + ((k) >> 6))  // LDS pad: k-groups land on distinct banks

struct SMemDense {
    float4 xs4[VOCAB + VOCAB / 64];  // x transposed: [k][4 rows], padded
    float part[16][4][32];           // [kg][r][jl]
};
union SMem {
    unsigned cnt[VOCAB];
    SMemDense d;
};

// ---------------------------------------------------------------------------
// Row-blocked dense phase (round-4 structure). Block tile: 4 rows x 32 cols;
// 256 thr = 16 kg x 16 jt; thread tile 4 rows x 2 cols. Weights: plain cached
// loads. Cross-phase in/out: atomic bypass loads/stores.
// ---------------------------------------------------------------------------
template <int K, int OUT, bool RELU, bool SSQ>
__device__ __forceinline__ void dense_phase(SMem& sm, int rg, int jw,
                                            const float* __restrict__ in,
                                            const float* __restrict__ W,
                                            const float* __restrict__ bias,
                                            float* __restrict__ outp,
                                            float* __restrict__ ssqp) {
    constexpr int KG = 16;
    constexpr int KC = K / KG;
    constexpr int JW = OUT / 32;
    const int b0 = rg * 4;
    const int tid = threadIdx.x;

    // ---- stage x (4 rows) transposed into LDS via bypass loads ----
    {
        constexpr int NK = K / 256;  // k's per thread
        float v[NK][4];
#pragma unroll
        for (int ko = 0; ko < NK; ++ko) {
            const int k = tid + 256 * ko;
#pragma unroll
            for (int r = 0; r < 4; ++r) v[ko][r] = ld_f32(&in[(size_t)(b0 + r) * K + k]);
        }
#pragma unroll
        for (int ko = 0; ko < NK; ++ko) {
            const int k = tid + 256 * ko;
            float4 x4 = {v[ko][0], v[ko][1], v[ko][2], v[ko][3]};
            sm.d.xs4[XSIDX(k)] = x4;
        }
    }
    __syncthreads();

    // ---- compute: thread (kg, jt) -> 4 rows x 2 cols over its K-chunk ----
    const int jt = tid & 15;
    const int kg = tid >> 4;
    const float* __restrict__ w = W + (size_t)(kg * KC) * OUT + jw * 32 + jt * 2;

    float2 acc0 = {0.f, 0.f}, acc1 = {0.f, 0.f}, acc2 = {0.f, 0.f}, acc3 = {0.f, 0.f};
#pragma unroll 8
    for (int ks = 0; ks < KC; ++ks) {
        const int k = kg * KC + ks;
        const float4 xv = sm.d.xs4[XSIDX(k)];                       // conflict-free bcast
        const float2 wv = *(const float2*)(w + (size_t)ks * OUT);   // cached, coalesced
        acc0.x = fmaf(xv.x, wv.x, acc0.x); acc0.y = fmaf(xv.x, wv.y, acc0.y);
        acc1.x = fmaf(xv.y, wv.x, acc1.x); acc1.y = fmaf(xv.y, wv.y, acc1.y);
        acc2.x = fmaf(xv.z, wv.x, acc2.x); acc2.y = fmaf(xv.z, wv.y, acc2.y);
        acc3.x = fmaf(xv.w, wv.x, acc3.x); acc3.y = fmaf(xv.w, wv.y, acc3.y);
    }

    *(float2*)&sm.d.part[kg][0][jt * 2] = acc0;
    *(float2*)&sm.d.part[kg][1][jt * 2] = acc1;
    *(float2*)&sm.d.part[kg][2][jt * 2] = acc2;
    *(float2*)&sm.d.part[kg][3][jt * 2] = acc3;
    __syncthreads();

    // ---- reduce 16 k-groups, bias, activation, bypass-store ----
    if (tid < 128) {
        const int r = tid >> 5;   // 0..3
        const int jl = tid & 31;  // 0..31
        float s = bias[jw * 32 + jl];
#pragma unroll
        for (int g = 0; g < KG; ++g) s += sm.d.part[g][r][jl];
        if (RELU) s = fmaxf(s, 0.0f);
        st_f32(&outp[(size_t)(b0 + r) * OUT + jw * 32 + jl], s);
        if constexpr (SSQ) {
            float s2 = s * s;
#pragma unroll
            for (int off = 16; off > 0; off >>= 1) s2 += __shfl_down(s2, off, 32);
            if (jl == 0) st_f32(&ssqp[(size_t)(b0 + r) * JW + jw], s2);
        }
    }
}

// ---------------------------------------------------------------------------
// Single fused kernel. Grid 256 x 256 (cooperative for co-residency; no
// grid.sync — per-rowgroup flags only).
// ---------------------------------------------------------------------------
__global__ __launch_bounds__(256) void fused_kernel(const int* __restrict__ tokens,
                                                    const float* __restrict__ W1,
                                                    const float* __restrict__ b1,
                                                    const float* __restrict__ W2,
                                                    const float* __restrict__ b2,
                                                    const float* __restrict__ W3,
                                                    const float* __restrict__ b3,
                                                    float* __restrict__ out,
                                                    unsigned* __restrict__ counts,
                                                    float* __restrict__ h1,
                                                    float* __restrict__ h2,
                                                    float* __restrict__ emb,
                                                    float* __restrict__ ssqp,
                                                    unsigned* __restrict__ flagH,
                                                    unsigned* __restrict__ flag1,
                                                    unsigned* __restrict__ flag2,
                                                    unsigned* __restrict__ flag3) {
    __shared__ SMem sm;
    const int blk = blockIdx.x;
    const int tid = threadIdx.x;

    // ===== Phase 1: token histograms (64 rows x 2 segments = 128 blocks) =====
    if (blk < BATCH * HSEG) {
        const int b = blk >> 1;
        const int seg = blk & 1;
#pragma unroll
        for (int i = 0; i < VOCAB / 256; ++i) sm.cnt[tid + 256 * i] = 0u;
        __syncthreads();

        const int4* __restrict__ t4 =
            reinterpret_cast<const int4*>(tokens + (size_t)b * TOK_T + seg * (TOK_T / HSEG));
#pragma unroll
        for (int i = 0; i < TOK_T / HSEG / 4 / 256; ++i) {  // 8 iterations
            int4 v = t4[i * 256 + tid];
            atomicAdd(&sm.cnt[v.x & (VOCAB - 1)], 1u);
            atomicAdd(&sm.cnt[v.y & (VOCAB - 1)], 1u);
            atomicAdd(&sm.cnt[v.z & (VOCAB - 1)], 1u);
            atomicAdd(&sm.cnt[v.w & (VOCAB - 1)], 1u);
        }
        __syncthreads();

        unsigned* __restrict__ row = counts + ((size_t)b * HSEG + seg) * VOCAB;
#pragma unroll
        for (int i = 0; i < 4; ++i) st_u32(&row[tid * 4 + i], sm.cnt[tid * 4 + i]);
        signal(&flagH[b]);
    }

    // ===== Phase 2: dense1 (1024->512, relu); pooled fused from counts =====
    {
        const int rg = blk >> 4;  // 16 rowgroups
        const int jw = blk & 15;  // 16 j-windows
        const int b0 = rg * 4;
        if (tid == 0) {
#pragma unroll
            for (int r = 0; r < 4; ++r) wait_one(&flagH[b0 + r], HSEG);
        }
        __syncthreads();

        // stage pooled (counts segsum / T) transposed into LDS
        {
            const float invT = 1.0f / (float)TOK_T;
            unsigned cc[4][8];
#pragma unroll
            for (int ko = 0; ko < 4; ++ko) {
                const int k = tid + 256 * ko;
#pragma unroll
                for (int r = 0; r < 4; ++r) {
                    cc[ko][2 * r + 0] = ld_u32(&counts[((size_t)(b0 + r) * HSEG + 0) * VOCAB + k]);
                    cc[ko][2 * r + 1] = ld_u32(&counts[((size_t)(b0 + r) * HSEG + 1) * VOCAB + k]);
                }
            }
#pragma unroll
            for (int ko = 0; ko < 4; ++ko) {
                const int k = tid + 256 * ko;
                float4 v;
                v.x = (float)(cc[ko][0] + cc[ko][1]) * invT;
                v.y = (float)(cc[ko][2] + cc[ko][3]) * invT;
                v.z = (float)(cc[ko][4] + cc[ko][5]) * invT;
                v.w = (float)(cc[ko][6] + cc[ko][7]) * invT;
                sm.d.xs4[XSIDX(k)] = v;
            }
        }
        __syncthreads();

        // compute + reduce + store (same structure as dense_phase, K=1024)
        constexpr int K = VOCAB, OUT = HIDDEN, KG = 16, KC = K / KG;
        const int jt = tid & 15;
        const int kg = tid >> 4;
        const float* __restrict__ w = W1 + (size_t)(kg * KC) * OUT + jw * 32 + jt * 2;
        float2 acc0 = {0.f, 0.f}, acc1 = {0.f, 0.f}, acc2 = {0.f, 0.f}, acc3 = {0.f, 0.f};
#pragma unroll 8
        for (int ks = 0; ks < KC; ++ks) {
            const int k = kg * KC + ks;
            const float4 xv = sm.d.xs4[XSIDX(k)];
            const float2 wv = *(const float2*)(w + (size_t)ks * OUT);
            acc0.x = fmaf(xv.x, wv.x, acc0.x); acc0.y = fmaf(xv.x, wv.y, acc0.y);
            acc1.x = fmaf(xv.y, wv.x, acc1.x); acc1.y = fmaf(xv.y, wv.y, acc1.y);
            acc2.x = fmaf(xv.z, wv.x, acc2.x); acc2.y = fmaf(xv.z, wv.y, acc2.y);
            acc3.x = fmaf(xv.w, wv.x, acc3.x); acc3.y = fmaf(xv.w, wv.y, acc3.y);
        }
        *(float2*)&sm.d.part[kg][0][jt * 2] = acc0;
        *(float2*)&sm.d.part[kg][1][jt * 2] = acc1;
        *(float2*)&sm.d.part[kg][2][jt * 2] = acc2;
        *(float2*)&sm.d.part[kg][3][jt * 2] = acc3;
        __syncthreads();
        if (tid < 128) {
            const int r = tid >> 5;
            const int jl = tid & 31;
            float s = b1[jw * 32 + jl];
#pragma unroll
            for (int g = 0; g < KG; ++g) s += sm.d.part[g][r][jl];
            st_f32(&h1[(size_t)(b0 + r) * OUT + jw * 32 + jl], fmaxf(s, 0.0f));
        }
        signal(&flag1[rg]);
    }

    // ===== Phase 3: dense2 (512->512, relu) =====
    {
        const int rg = blk >> 4;
        const int jw = blk & 15;
        if (tid == 0) wait_one(&flag1[rg], 16);
        __syncthreads();
        dense_phase<HIDDEN, HIDDEN, true, false>(sm, rg, jw, h1, W2, b2, h2, nullptr);
        signal(&flag2[rg]);
    }

    // ===== Phase 4: dense3 (512->256) + ssq partials (128 blocks) =====
    if (blk < (BATCH / 4) * (EMBED / 32)) {
        const int rg = blk >> 3;  // 16 rowgroups
        const int jw = blk & 7;   // 8 j-windows
        if (tid == 0) wait_one(&flag2[rg], 16);
        __syncthreads();
        dense_phase<HIDDEN, EMBED, false, true>(sm, rg, jw, h2, W3, b3, emb, ssqp);
        signal(&flag3[rg]);
    }

    // ===== Phase 5: L2 normalize (64 blocks, one row each) =====
    if (blk < BATCH) {
        const int b = blk;
        if (tid == 0) wait_one(&flag3[b >> 2], 8);
        __syncthreads();
        float total = 0.0f;
#pragma unroll
        for (int i = 0; i < EMBED / 32; ++i) total += ld_f32(&ssqp[(size_t)b * (EMBED / 32) + i]);
        const float v = ld_f32(&emb[(size_t)b * EMBED + tid]);
        out[(size_t)b * EMBED + tid] = v / fmaxf(sqrtf(total), 1e-12f);  // F.normalize eps
    }
}

// ---------------------------------------------------------------------------
// Launch: tiny flag-clear memset + one cooperative kernel.
// ---------------------------------------------------------------------------
extern "C" void kernel_launch(void* const* d_in, const int* in_sizes, int n_in,
                              void* d_out, int out_size, void* d_ws, size_t ws_size,
                              hipStream_t stream) {
    const int*   tokens = (const int*)d_in[0];   // [64,16384], values in [0,1024)
    const float* W1     = (const float*)d_in[1]; // [1024,512]
    const float* b1     = (const float*)d_in[2]; // [512]
    const float* W2     = (const float*)d_in[3]; // [512,512]
    const float* b2     = (const float*)d_in[4]; // [512]
    const float* W3     = (const float*)d_in[5]; // [512,256]
    const float* b3     = (const float*)d_in[6]; // [256]
    float*       out    = (float*)d_out;         // [64,256]

    // Workspace (fully rewritten every call).
    unsigned* counts = (unsigned*)d_ws;                                  // [64][2][1024] u32
    float*    h1     = (float*)(counts + (size_t)BATCH * HSEG * VOCAB);  // [64][512]
    float*    h2     = h1 + (size_t)BATCH * HIDDEN;                      // [64][512]
    float*    emb    = h2 + (size_t)BATCH * HIDDEN;                      // [64][256]
    float*    ssqp   = emb + (size_t)BATCH * EMBED;                      // [64][8]
    unsigned* flagH  = (unsigned*)(ssqp + (size_t)BATCH * (EMBED / 32)); // [64]
    unsigned* flag1  = flagH + BATCH;                                    // [16]
    unsigned* flag2  = flag1 + 16;                                       // [16]
    unsigned* flag3  = flag2 + 16;                                       // [16]

    // Flags must start at 0 every call (ws is poisoned / left dirty).
    hipMemsetAsync((void*)flagH, 0, (BATCH + 48) * sizeof(unsigned), stream);

    void* args[] = {&tokens, &W1, &b1, &W2, &b2, &W3, &b3, &out,
                    &counts, &h1, &h2, &emb, &ssqp,
                    &flagH, &flag1, &flag2, &flag3};
    hipLaunchCooperativeKernel((const void*)fused_kernel, dim3(256), dim3(256),
                               args, 0, stream);
}

// Round 8
// 45.705 us; speedup vs baseline: 2.9922x; 1.2748x over previous
//
#include <hip/hip_runtime.h>
#include <hip/hip_bf16.h>

// SpeakerEmbedder: token histogram (bag-of-words mean) -> 3-layer MLP -> L2 normalize.
// B=64, T=16384, VOCAB=1024, HIDDEN=512, EMBED=256. All math in fp32.
//
// Round-8: single REGULAR launch (grid 256 = CU count -> all blocks resident;
// no cooperative-launch overhead), phases chained by per-row/rowgroup flags
// (no grid.sync -> no L2 invalidate -> weights stay L2-cached).
// Handoff protocol:
//   producer: plain compute -> agent-scope (sc1, write-through-to-MALL) stores
//             -> s_waitcnt vmcnt(0) -> __syncthreads -> thread0 fetch_add flag.
//   consumer: thread0 relaxed-spins on flag -> __syncthreads -> PLAIN CACHED
//             vectorized loads (first touch of those lines post-flag: L2 miss
//             refills from MALL = fresh; r7's serialized atomic bypass loads
//             were the perf bug).
// Flags (448 B) zeroed by one tiny hipMemsetAsync node per call.

#define VOCAB 1024
#define HIDDEN 512
#define EMBED 256
#define TOK_T 16384
#define BATCH 64
#define HSEG 4  // histogram segments per row (all 256 blocks do hist)

#define AGENT __HIP_MEMORY_SCOPE_AGENT

__device__ __forceinline__ void st_u32(unsigned* p, unsigned v) {
    __hip_atomic_store(p, v, __ATOMIC_RELAXED, AGENT);  // sc1: through to MALL
}
__device__ __forceinline__ void st_f32(float* p, float v) {
    __hip_atomic_store(p, v, __ATOMIC_RELAXED, AGENT);
}

// All threads arrive; thread0 publishes one arrival on flag.
__device__ __forceinline__ void signal(unsigned* flag) {
    asm volatile("s_waitcnt vmcnt(0)" ::: "memory");  // stores acked at coherence point
    __syncthreads();
    if (threadIdx.x == 0) __hip_atomic_fetch_add(flag, 1u, __ATOMIC_RELAXED, AGENT);
}
__device__ __forceinline__ void wait_flag(const unsigned* flag, unsigned target) {
    if (threadIdx.x == 0) {
        while (__hip_atomic_load(flag, __ATOMIC_RELAXED, AGENT) != target)
            __builtin_amdgcn_s_sleep(1);
    }
    __syncthreads();  // orders all waves' subsequent loads after the flag
}

#define XSIDX(k) ((k) + ((k) >> 6))  // LDS pad: k-groups land on distinct banks

struct SMemDense {
    float4 xs4[VOCAB + VOCAB / 64];  // x transposed: [k][4 rows], padded
    float part[16][4][32];           // [kg][r][jl]
};
union SMem {
    unsigned cnt[VOCAB];
    SMemDense d;
};

// ---------------------------------------------------------------------------
// Row-blocked dense phase (round-4/5 structure). Block tile: 4 rows x 32 cols;
// 256 thr = 16 kg x 16 jt; thread tile 4 rows x 2 cols. Staging: plain cached
// coalesced loads. Output: sc1 stores.
// ---------------------------------------------------------------------------
template <int K, int OUT, bool RELU, bool SSQ>
__device__ __forceinline__ void dense_phase(SMem& sm, int rg, int jw,
                                            const float* __restrict__ in,
                                            const float* __restrict__ W,
                                            const float* __restrict__ bias,
                                            float* __restrict__ outp,
                                            float* __restrict__ ssqp) {
    constexpr int KG = 16;
    constexpr int KC = K / KG;
    constexpr int JW = OUT / 32;
    const int b0 = rg * 4;
    const int tid = threadIdx.x;

    // ---- stage x (4 rows) transposed into LDS (plain cached loads) ----
    for (int k = tid; k < K; k += 256) {
        float4 v;
        v.x = in[(size_t)(b0 + 0) * K + k];
        v.y = in[(size_t)(b0 + 1) * K + k];
        v.z = in[(size_t)(b0 + 2) * K + k];
        v.w = in[(size_t)(b0 + 3) * K + k];
        sm.d.xs4[XSIDX(k)] = v;
    }
    __syncthreads();

    // ---- compute: thread (kg, jt) -> 4 rows x 2 cols over its K-chunk ----
    const int jt = tid & 15;
    const int kg = tid >> 4;
    const float* __restrict__ w = W + (size_t)(kg * KC) * OUT + jw * 32 + jt * 2;

    float2 acc0 = {0.f, 0.f}, acc1 = {0.f, 0.f}, acc2 = {0.f, 0.f}, acc3 = {0.f, 0.f};
#pragma unroll 8
    for (int ks = 0; ks < KC; ++ks) {
        const int k = kg * KC + ks;
        const float4 xv = sm.d.xs4[XSIDX(k)];                       // conflict-free bcast
        const float2 wv = *(const float2*)(w + (size_t)ks * OUT);   // cached, coalesced
        acc0.x = fmaf(xv.x, wv.x, acc0.x); acc0.y = fmaf(xv.x, wv.y, acc0.y);
        acc1.x = fmaf(xv.y, wv.x, acc1.x); acc1.y = fmaf(xv.y, wv.y, acc1.y);
        acc2.x = fmaf(xv.z, wv.x, acc2.x); acc2.y = fmaf(xv.z, wv.y, acc2.y);
        acc3.x = fmaf(xv.w, wv.x, acc3.x); acc3.y = fmaf(xv.w, wv.y, acc3.y);
    }

    *(float2*)&sm.d.part[kg][0][jt * 2] = acc0;
    *(float2*)&sm.d.part[kg][1][jt * 2] = acc1;
    *(float2*)&sm.d.part[kg][2][jt * 2] = acc2;
    *(float2*)&sm.d.part[kg][3][jt * 2] = acc3;
    __syncthreads();

    // ---- reduce 16 k-groups, bias, activation, sc1 store ----
    if (tid < 128) {
        const int r = tid >> 5;   // 0..3
        const int jl = tid & 31;  // 0..31
        float s = bias[jw * 32 + jl];
#pragma unroll
        for (int g = 0; g < KG; ++g) s += sm.d.part[g][r][jl];
        if (RELU) s = fmaxf(s, 0.0f);
        st_f32(&outp[(size_t)(b0 + r) * OUT + jw * 32 + jl], s);
        if constexpr (SSQ) {
            float s2 = s * s;
#pragma unroll
            for (int off = 16; off > 0; off >>= 1) s2 += __shfl_down(s2, off, 32);
            if (jl == 0) st_f32(&ssqp[(size_t)(b0 + r) * JW + jw], s2);
        }
    }
}

// ---------------------------------------------------------------------------
// Single fused kernel; grid MUST be 256 x 256 (all blocks co-resident: 1/CU).
// ---------------------------------------------------------------------------
__global__ __launch_bounds__(256) void fused_kernel(const int* __restrict__ tokens,
                                                    const float* __restrict__ W1,
                                                    const float* __restrict__ b1,
                                                    const float* __restrict__ W2,
                                                    const float* __restrict__ b2,
                                                    const float* __restrict__ W3,
                                                    const float* __restrict__ b3,
                                                    float* __restrict__ out,
                                                    unsigned* __restrict__ counts,
                                                    float* __restrict__ h1,
                                                    float* __restrict__ h2,
                                                    float* __restrict__ emb,
                                                    float* __restrict__ ssqp,
                                                    unsigned* __restrict__ flagH,
                                                    unsigned* __restrict__ flag1,
                                                    unsigned* __restrict__ flag2,
                                                    unsigned* __restrict__ flag3) {
    __shared__ SMem sm;
    const int blk = blockIdx.x;
    const int tid = threadIdx.x;

    // ===== Phase 1: token histograms (64 rows x 4 segments = 256 blocks) =====
    {
        const int b = blk >> 2;
        const int seg = blk & 3;
#pragma unroll
        for (int i = 0; i < VOCAB / 256; ++i) sm.cnt[tid + 256 * i] = 0u;
        __syncthreads();

        const int4* __restrict__ t4 =
            reinterpret_cast<const int4*>(tokens + (size_t)b * TOK_T + seg * (TOK_T / HSEG));
#pragma unroll
        for (int i = 0; i < TOK_T / HSEG / 4 / 256; ++i) {  // 4 iterations
            int4 v = t4[i * 256 + tid];
            atomicAdd(&sm.cnt[v.x & (VOCAB - 1)], 1u);
            atomicAdd(&sm.cnt[v.y & (VOCAB - 1)], 1u);
            atomicAdd(&sm.cnt[v.z & (VOCAB - 1)], 1u);
            atomicAdd(&sm.cnt[v.w & (VOCAB - 1)], 1u);
        }
        __syncthreads();

        unsigned* __restrict__ row = counts + ((size_t)b * HSEG + seg) * VOCAB;
#pragma unroll
        for (int i = 0; i < 4; ++i) st_u32(&row[tid * 4 + i], sm.cnt[tid * 4 + i]);
        signal(&flagH[b]);
    }

    // ===== Phase 2: dense1 (1024->512, relu); pooled fused from counts =====
    {
        const int rg = blk >> 4;  // 16 rowgroups
        const int jw = blk & 15;  // 16 j-windows
        const int b0 = rg * 4;
        if (tid == 0) {
#pragma unroll
            for (int r = 0; r < 4; ++r)
                while (__hip_atomic_load(&flagH[b0 + r], __ATOMIC_RELAXED, AGENT) != HSEG)
                    __builtin_amdgcn_s_sleep(1);
        }
        __syncthreads();

        // stage pooled (counts segsum / T) transposed into LDS (plain loads)
        {
            const float invT = 1.0f / (float)TOK_T;
#pragma unroll
            for (int ko = 0; ko < 4; ++ko) {
                const int k = tid + 256 * ko;
                float4 v;
#pragma unroll
                for (int r = 0; r < 4; ++r) {
                    const unsigned* __restrict__ cr = counts + (size_t)(b0 + r) * HSEG * VOCAB;
                    unsigned s = cr[k] + cr[k + VOCAB] + cr[k + 2 * VOCAB] + cr[k + 3 * VOCAB];
                    (&v.x)[r] = (float)s * invT;
                }
                sm.d.xs4[XSIDX(k)] = v;
            }
        }
        __syncthreads();

        constexpr int K = VOCAB, OUT = HIDDEN, KG = 16, KC = K / KG;
        const int jt = tid & 15;
        const int kg = tid >> 4;
        const float* __restrict__ w = W1 + (size_t)(kg * KC) * OUT + jw * 32 + jt * 2;
        float2 acc0 = {0.f, 0.f}, acc1 = {0.f, 0.f}, acc2 = {0.f, 0.f}, acc3 = {0.f, 0.f};
#pragma unroll 8
        for (int ks = 0; ks < KC; ++ks) {
            const int k = kg * KC + ks;
            const float4 xv = sm.d.xs4[XSIDX(k)];
            const float2 wv = *(const float2*)(w + (size_t)ks * OUT);
            acc0.x = fmaf(xv.x, wv.x, acc0.x); acc0.y = fmaf(xv.x, wv.y, acc0.y);
            acc1.x = fmaf(xv.y, wv.x, acc1.x); acc1.y = fmaf(xv.y, wv.y, acc1.y);
            acc2.x = fmaf(xv.z, wv.x, acc2.x); acc2.y = fmaf(xv.z, wv.y, acc2.y);
            acc3.x = fmaf(xv.w, wv.x, acc3.x); acc3.y = fmaf(xv.w, wv.y, acc3.y);
        }
        *(float2*)&sm.d.part[kg][0][jt * 2] = acc0;
        *(float2*)&sm.d.part[kg][1][jt * 2] = acc1;
        *(float2*)&sm.d.part[kg][2][jt * 2] = acc2;
        *(float2*)&sm.d.part[kg][3][jt * 2] = acc3;
        __syncthreads();
        if (tid < 128) {
            const int r = tid >> 5;
            const int jl = tid & 31;
            float s = b1[jw * 32 + jl];
#pragma unroll
            for (int g = 0; g < KG; ++g) s += sm.d.part[g][r][jl];
            st_f32(&h1[(size_t)(b0 + r) * OUT + jw * 32 + jl], fmaxf(s, 0.0f));
        }
        signal(&flag1[rg]);
    }

    // ===== Phase 3: dense2 (512->512, relu) =====
    {
        const int rg = blk >> 4;
        const int jw = blk & 15;
        wait_flag(&flag1[rg], 16);
        dense_phase<HIDDEN, HIDDEN, true, false>(sm, rg, jw, h1, W2, b2, h2, nullptr);
        signal(&flag2[rg]);
    }

    // ===== Phase 4: dense3 (512->256) + ssq partials (blocks 0-127) =====
    if (blk < (BATCH / 4) * (EMBED / 32)) {
        const int rg = blk >> 3;  // 16 rowgroups
        const int jw = blk & 7;   // 8 j-windows
        wait_flag(&flag2[rg], 16);
        dense_phase<HIDDEN, EMBED, false, true>(sm, rg, jw, h2, W3, b3, emb, ssqp);
        signal(&flag3[rg]);
    }

    // ===== Phase 5: L2 normalize (blocks 0-63, one row each) =====
    if (blk < BATCH) {
        const int b = blk;
        wait_flag(&flag3[b >> 2], 8);
        float total = 0.0f;
#pragma unroll
        for (int i = 0; i < EMBED / 32; ++i) total += ssqp[(size_t)b * (EMBED / 32) + i];
        const float v = emb[(size_t)b * EMBED + tid];
        out[(size_t)b * EMBED + tid] = v / fmaxf(sqrtf(total), 1e-12f);  // F.normalize eps
    }
}

// ---------------------------------------------------------------------------
// Launch: tiny flag-clear memset + ONE regular kernel launch.
// ---------------------------------------------------------------------------
extern "C" void kernel_launch(void* const* d_in, const int* in_sizes, int n_in,
                              void* d_out, int out_size, void* d_ws, size_t ws_size,
                              hipStream_t stream) {
    const int*   tokens = (const int*)d_in[0];   // [64,16384], values in [0,1024)
    const float* W1     = (const float*)d_in[1]; // [1024,512]
    const float* b1     = (const float*)d_in[2]; // [512]
    const float* W2     = (const float*)d_in[3]; // [512,512]
    const float* b2     = (const float*)d_in[4]; // [512]
    const float* W3     = (const float*)d_in[5]; // [512,256]
    const float* b3     = (const float*)d_in[6]; // [256]
    float*       out    = (float*)d_out;         // [64,256]

    // Workspace (fully rewritten every call, guarded by flags).
    unsigned* counts = (unsigned*)d_ws;                                  // [64][4][1024] u32
    float*    h1     = (float*)(counts + (size_t)BATCH * HSEG * VOCAB);  // [64][512]
    float*    h2     = h1 + (size_t)BATCH * HIDDEN;                      // [64][512]
    float*    emb    = h2 + (size_t)BATCH * HIDDEN;                      // [64][256]
    float*    ssqp   = emb + (size_t)BATCH * EMBED;                      // [64][8]
    unsigned* flagH  = (unsigned*)(ssqp + (size_t)BATCH * (EMBED / 32)); // [64]
    unsigned* flag1  = flagH + BATCH;                                    // [16]
    unsigned* flag2  = flag1 + 16;                                       // [16]
    unsigned* flag3  = flag2 + 16;                                       // [16]

    // Flags must start at 0 every call.
    hipMemsetAsync((void*)flagH, 0, (BATCH + 48) * sizeof(unsigned), stream);

    fused_kernel<<<256, 256, 0, stream>>>(tokens, W1, b1, W2, b2, W3, b3, out,
                                          counts, h1, h2, emb, ssqp,
                                          flagH, flag1, flag2, flag3);
}

// Round 9
// 41.566 us; speedup vs baseline: 3.2901x; 1.0996x over previous
//
#include <hip/hip_runtime.h>
#include <hip/hip_bf16.h>

// SpeakerEmbedder: token histogram (bag-of-words mean) -> 3-layer MLP -> L2 normalize.
// B=64, T=16384, VOCAB=1024, HIDDEN=512, EMBED=256. All math in fp32.
//
// Round-9: ALL inter-block sync protocols lost to per-launch overhead
// (grid.sync 137us, bypass-flag 58us, sc1-flag 46us vs 5-kernel 26.4us;
// flag versions bottlenecked on same-cache-line device atomics at the MALL).
// New structure: ONE block owns TWO batch rows END-TO-END. All intermediates
// (counts/pooled/h1/h2/emb) live in LDS; phases separated only by
// __syncthreads(). 32 blocks x 1024 threads, one regular launch, no
// workspace, no flags, no memset. Cost model: dense VALU ~6us on 32 CUs
// (binding), weight L2 re-stream 14.7 MB/XCD ~3.4us (hidden), hist ~1us.

#define VOCAB 1024
#define HIDDEN 512
#define EMBED 256
#define TOK_T 16384
#define BATCH 64
#define NT 1024            // threads per block
#define NB (BATCH / 2)     // 32 blocks, 2 rows each

// ---------------------------------------------------------------------------
// Dense layer on 2 rows resident in LDS.
//   xin[k] = {x_row0[k], x_row1[k]}  (float2, LDS)
//   thread (kg, jt): cols [jt*4, jt*4+4) of both rows over k-chunk kg.
//   W load: one float4/k, lanes jt consecutive -> 1KB coalesced per wave.
//   x load: ds_read_b64, wave-uniform address -> broadcast, conflict-free.
//   reduce: red[kg][r][j] in LDS, combined by 2*OUT threads (+bias, act),
//   output written as yout[j*2+r] (= float2[j] = next layer's xin layout).
// ---------------------------------------------------------------------------
template <int K, int OUT, bool RELU>
__device__ __forceinline__ void dense_layer(const float2* __restrict__ xin,
                                            const float* __restrict__ W,
                                            const float* __restrict__ bias,
                                            float* __restrict__ red,   // >= (NT/(OUT/4))*2*OUT floats
                                            float* __restrict__ yout,  // [OUT*2], layout [j][r]
                                            int tid) {
    constexpr int JT = OUT / 4;   // j-threads (one float4 of cols each)
    constexpr int KG = NT / JT;   // k-groups
    constexpr int KC = K / KG;    // k per thread
    const int jt = tid % JT;      // wave-contiguous (JT is 64 or 128)
    const int kg = tid / JT;      // wave-uniform

    const float* __restrict__ w = W + (size_t)(kg * KC) * OUT + jt * 4;
    const float2* __restrict__ xk = xin + kg * KC;

    float4 a0 = {0.f, 0.f, 0.f, 0.f}, a1 = {0.f, 0.f, 0.f, 0.f};
#pragma unroll 8
    for (int ks = 0; ks < KC; ++ks) {
        const float2 x = xk[ks];                                        // LDS bcast
        const float4 wv = *reinterpret_cast<const float4*>(w + (size_t)ks * OUT);
        a0.x = fmaf(x.x, wv.x, a0.x); a0.y = fmaf(x.x, wv.y, a0.y);
        a0.z = fmaf(x.x, wv.z, a0.z); a0.w = fmaf(x.x, wv.w, a0.w);
        a1.x = fmaf(x.y, wv.x, a1.x); a1.y = fmaf(x.y, wv.y, a1.y);
        a1.z = fmaf(x.y, wv.z, a1.z); a1.w = fmaf(x.y, wv.w, a1.w);
    }

    float4* red4 = reinterpret_cast<float4*>(red);
    red4[(kg * 2 + 0) * JT + jt] = a0;   // red[kg][0][jt*4..]
    red4[(kg * 2 + 1) * JT + jt] = a1;   // red[kg][1][jt*4..]
    __syncthreads();

    // combine KG partials; 2*OUT threads, r wave-uniform, j lane-consecutive
    if (tid < 2 * OUT) {
        const int r = tid / OUT;
        const int j = tid % OUT;
        float s = bias[j];
#pragma unroll
        for (int g = 0; g < KG; ++g) s += red[(g * 2 + r) * OUT + j];
        if (RELU) s = fmaxf(s, 0.0f);
        yout[j * 2 + r] = s;   // stride-8B write: 2-way alias, free
    }
    __syncthreads();
}

// ---------------------------------------------------------------------------
// One block = rows {2*blk, 2*blk+1}, end-to-end. No global intermediates.
// ---------------------------------------------------------------------------
__global__ __launch_bounds__(NT) void fused_kernel(const int* __restrict__ tokens,
                                                   const float* __restrict__ W1,
                                                   const float* __restrict__ b1,
                                                   const float* __restrict__ W2,
                                                   const float* __restrict__ b2,
                                                   const float* __restrict__ W3,
                                                   const float* __restrict__ b3,
                                                   float* __restrict__ out) {
    __shared__ unsigned cnt[2 * VOCAB];        //  8 KB  [r][v]
    __shared__ float2   xs2[VOCAB];            //  8 KB  pooled, [k]{r0,r1}
    __shared__ float    red[8 * 2 * HIDDEN];   // 32 KB  k-group partials (all layers)
    __shared__ float    h1f[HIDDEN * 2];       //  4 KB  [j][r]
    __shared__ float    h2f[HIDDEN * 2];       //  4 KB
    __shared__ float    embs[EMBED * 2];       //  2 KB  [j][r]
    __shared__ float    wss[8];                // per-wave ssq partials

    const int tid = threadIdx.x;
    const int b0 = blockIdx.x * 2;

    // ===== Phase 1: token histograms for both rows (LDS atomics) =====
    cnt[tid] = 0u;
    cnt[tid + VOCAB] = 0u;
    __syncthreads();
#pragma unroll
    for (int r = 0; r < 2; ++r) {
        const int4* __restrict__ t4 =
            reinterpret_cast<const int4*>(tokens + (size_t)(b0 + r) * TOK_T);
        unsigned* __restrict__ c = cnt + r * VOCAB;
#pragma unroll
        for (int i = 0; i < TOK_T / 4 / NT; ++i) {  // 4 iterations
            int4 v = t4[tid + NT * i];
            atomicAdd(&c[v.x & (VOCAB - 1)], 1u);
            atomicAdd(&c[v.y & (VOCAB - 1)], 1u);
            atomicAdd(&c[v.z & (VOCAB - 1)], 1u);
            atomicAdd(&c[v.w & (VOCAB - 1)], 1u);
        }
    }
    __syncthreads();

    // ===== Phase 2: counts -> pooled (transpose to [k]{r0,r1}) =====
    {
        const float invT = 1.0f / (float)TOK_T;
        float2 p;
        p.x = (float)cnt[tid] * invT;
        p.y = (float)cnt[tid + VOCAB] * invT;
        xs2[tid] = p;
    }
    __syncthreads();

    // ===== Phases 3-5: MLP, everything in LDS =====
    dense_layer<VOCAB, HIDDEN, true>(xs2, W1, b1, red, h1f, tid);
    dense_layer<HIDDEN, HIDDEN, true>(reinterpret_cast<const float2*>(h1f),
                                      W2, b2, red, h2f, tid);
    dense_layer<HIDDEN, EMBED, false>(reinterpret_cast<const float2*>(h2f),
                                      W3, b3, red, embs, tid);

    // ===== Phase 6: L2 normalize both rows, write out =====
    float v = 0.0f;
    int r = 0, j = 0;
    if (tid < 2 * EMBED) {        // 512 threads; waves 0-3 -> r0, 4-7 -> r1
        r = tid >> 8;
        j = tid & (EMBED - 1);
        v = embs[j * 2 + r];
    }
    float ss = v * v;
#pragma unroll
    for (int off = 32; off > 0; off >>= 1) ss += __shfl_down(ss, off);  // wave64
    if (tid < 2 * EMBED && (tid & 63) == 0) wss[tid >> 6] = ss;
    __syncthreads();
    if (tid < 2 * EMBED) {
        const float total = wss[r * 4 + 0] + wss[r * 4 + 1] + wss[r * 4 + 2] + wss[r * 4 + 3];
        out[(size_t)(b0 + r) * EMBED + j] = v / fmaxf(sqrtf(total), 1e-12f);  // F.normalize eps
    }
}

// ---------------------------------------------------------------------------
// Launch: ONE regular kernel. No workspace, no memset.
// ---------------------------------------------------------------------------
extern "C" void kernel_launch(void* const* d_in, const int* in_sizes, int n_in,
                              void* d_out, int out_size, void* d_ws, size_t ws_size,
                              hipStream_t stream) {
    const int*   tokens = (const int*)d_in[0];   // [64,16384], values in [0,1024)
    const float* W1     = (const float*)d_in[1]; // [1024,512]
    const float* b1     = (const float*)d_in[2]; // [512]
    const float* W2     = (const float*)d_in[3]; // [512,512]
    const float* b2     = (const float*)d_in[4]; // [512]
    const float* W3     = (const float*)d_in[5]; // [512,256]
    const float* b3     = (const float*)d_in[6]; // [256]
    float*       out    = (float*)d_out;         // [64,256]
    (void)d_ws; (void)ws_size;

    fused_kernel<<<NB, NT, 0, stream>>>(tokens, W1, b1, W2, b2, W3, b3, out);
}

// Round 10
// 28.323 us; speedup vs baseline: 4.8286x; 1.4676x over previous
//
#include <hip/hip_runtime.h>
#include <hip/hip_bf16.h>

// SpeakerEmbedder: token histogram (bag-of-words mean) -> 3-layer MLP -> L2 normalize.
// B=64, T=16384, VOCAB=1024, HIDDEN=512, EMBED=256. All math in fp32.
//
// Round-10: r9 proved communication-free full fusion hits a per-CU L2 wall
// (every block streams all 3.67MB of W through one CU's ~144GB/s L2 port ->
// >=25us). So j-partitioned phases + flags are required. r8's flag protocol
// was correct but its flags shared cache lines (16 dwords on ONE 64B line ->
// ~500 serialized MALL RMW/poll ops per handoff). THIS ROUND: identical to
// r8 except every flag lives on its own 128-B line.
// Handoff protocol (unchanged from r8):
//   producer: sc1 (agent-scope) stores -> s_waitcnt vmcnt(0) -> __syncthreads
//             -> thread0 fetch_add(flag).
//   consumer: thread0 spins on flag -> __syncthreads -> plain cached loads
//             (first touch post-flag misses L2, refills fresh from MALL).

#define VOCAB 1024
#define HIDDEN 512
#define EMBED 256
#define TOK_T 16384
#define BATCH 64
#define HSEG 4  // histogram segments per row (all 256 blocks do hist)

#define AGENT __HIP_MEMORY_SCOPE_AGENT

struct alignas(128) Flag { unsigned v; };  // one flag per 128-B line (sizeof==128)

__device__ __forceinline__ void st_u32(unsigned* p, unsigned v) {
    __hip_atomic_store(p, v, __ATOMIC_RELAXED, AGENT);  // sc1: through to MALL
}
__device__ __forceinline__ void st_f32(float* p, float v) {
    __hip_atomic_store(p, v, __ATOMIC_RELAXED, AGENT);
}

// All threads arrive; thread0 publishes one arrival on flag.
__device__ __forceinline__ void signal(Flag* flag) {
    asm volatile("s_waitcnt vmcnt(0)" ::: "memory");  // stores acked at coherence point
    __syncthreads();
    if (threadIdx.x == 0) __hip_atomic_fetch_add(&flag->v, 1u, __ATOMIC_RELAXED, AGENT);
}
__device__ __forceinline__ void wait_flag(const Flag* flag, unsigned target) {
    if (threadIdx.x == 0) {
        while (__hip_atomic_load(&flag->v, __ATOMIC_RELAXED, AGENT) != target)
            __builtin_amdgcn_s_sleep(1);
    }
    __syncthreads();  // orders all waves' subsequent loads after the flag
}

#define XSIDX(k) ((k) + ((k) >> 6))  // LDS pad: k-groups land on distinct banks

struct SMemDense {
    float4 xs4[VOCAB + VOCAB / 64];  // x transposed: [k][4 rows], padded
    float part[16][4][32];           // [kg][r][jl]
};
union SMem {
    unsigned cnt[VOCAB];
    SMemDense d;
};

// ---------------------------------------------------------------------------
// Row-blocked dense phase. Block tile: 4 rows x 32 cols; 256 thr = 16 kg x
// 16 jt; thread tile 4 rows x 2 cols. Staging: plain cached coalesced loads.
// Output: sc1 stores.
// ---------------------------------------------------------------------------
template <int K, int OUT, bool RELU, bool SSQ>
__device__ __forceinline__ void dense_phase(SMem& sm, int rg, int jw,
                                            const float* __restrict__ in,
                                            const float* __restrict__ W,
                                            const float* __restrict__ bias,
                                            float* __restrict__ outp,
                                            float* __restrict__ ssqp) {
    constexpr int KG = 16;
    constexpr int KC = K / KG;
    constexpr int JW = OUT / 32;
    const int b0 = rg * 4;
    const int tid = threadIdx.x;

    // ---- stage x (4 rows) transposed into LDS (plain cached loads) ----
    for (int k = tid; k < K; k += 256) {
        float4 v;
        v.x = in[(size_t)(b0 + 0) * K + k];
        v.y = in[(size_t)(b0 + 1) * K + k];
        v.z = in[(size_t)(b0 + 2) * K + k];
        v.w = in[(size_t)(b0 + 3) * K + k];
        sm.d.xs4[XSIDX(k)] = v;
    }
    __syncthreads();

    // ---- compute: thread (kg, jt) -> 4 rows x 2 cols over its K-chunk ----
    const int jt = tid & 15;
    const int kg = tid >> 4;
    const float* __restrict__ w = W + (size_t)(kg * KC) * OUT + jw * 32 + jt * 2;

    float2 acc0 = {0.f, 0.f}, acc1 = {0.f, 0.f}, acc2 = {0.f, 0.f}, acc3 = {0.f, 0.f};
#pragma unroll 8
    for (int ks = 0; ks < KC; ++ks) {
        const int k = kg * KC + ks;
        const float4 xv = sm.d.xs4[XSIDX(k)];                       // conflict-free bcast
        const float2 wv = *(const float2*)(w + (size_t)ks * OUT);   // cached, coalesced
        acc0.x = fmaf(xv.x, wv.x, acc0.x); acc0.y = fmaf(xv.x, wv.y, acc0.y);
        acc1.x = fmaf(xv.y, wv.x, acc1.x); acc1.y = fmaf(xv.y, wv.y, acc1.y);
        acc2.x = fmaf(xv.z, wv.x, acc2.x); acc2.y = fmaf(xv.z, wv.y, acc2.y);
        acc3.x = fmaf(xv.w, wv.x, acc3.x); acc3.y = fmaf(xv.w, wv.y, acc3.y);
    }

    *(float2*)&sm.d.part[kg][0][jt * 2] = acc0;
    *(float2*)&sm.d.part[kg][1][jt * 2] = acc1;
    *(float2*)&sm.d.part[kg][2][jt * 2] = acc2;
    *(float2*)&sm.d.part[kg][3][jt * 2] = acc3;
    __syncthreads();

    // ---- reduce 16 k-groups, bias, activation, sc1 store ----
    if (tid < 128) {
        const int r = tid >> 5;   // 0..3
        const int jl = tid & 31;  // 0..31
        float s = bias[jw * 32 + jl];
#pragma unroll
        for (int g = 0; g < KG; ++g) s += sm.d.part[g][r][jl];
        if (RELU) s = fmaxf(s, 0.0f);
        st_f32(&outp[(size_t)(b0 + r) * OUT + jw * 32 + jl], s);
        if constexpr (SSQ) {
            float s2 = s * s;
#pragma unroll
            for (int off = 16; off > 0; off >>= 1) s2 += __shfl_down(s2, off, 32);
            if (jl == 0) st_f32(&ssqp[(size_t)(b0 + r) * JW + jw], s2);
        }
    }
}

// ---------------------------------------------------------------------------
// Single fused kernel; grid MUST be 256 x 256 (all blocks co-resident: 1/CU).
// ---------------------------------------------------------------------------
__global__ __launch_bounds__(256) void fused_kernel(const int* __restrict__ tokens,
                                                    const float* __restrict__ W1,
                                                    const float* __restrict__ b1,
                                                    const float* __restrict__ W2,
                                                    const float* __restrict__ b2,
                                                    const float* __restrict__ W3,
                                                    const float* __restrict__ b3,
                                                    float* __restrict__ out,
                                                    unsigned* __restrict__ counts,
                                                    float* __restrict__ h1,
                                                    float* __restrict__ h2,
                                                    float* __restrict__ emb,
                                                    float* __restrict__ ssqp,
                                                    Flag* __restrict__ flagH,
                                                    Flag* __restrict__ flag1,
                                                    Flag* __restrict__ flag2,
                                                    Flag* __restrict__ flag3) {
    __shared__ SMem sm;
    const int blk = blockIdx.x;
    const int tid = threadIdx.x;

    // ===== Phase 1: token histograms (64 rows x 4 segments = 256 blocks) =====
    {
        const int b = blk >> 2;
        const int seg = blk & 3;
#pragma unroll
        for (int i = 0; i < VOCAB / 256; ++i) sm.cnt[tid + 256 * i] = 0u;
        __syncthreads();

        const int4* __restrict__ t4 =
            reinterpret_cast<const int4*>(tokens + (size_t)b * TOK_T + seg * (TOK_T / HSEG));
#pragma unroll
        for (int i = 0; i < TOK_T / HSEG / 4 / 256; ++i) {  // 4 iterations
            int4 v = t4[i * 256 + tid];
            atomicAdd(&sm.cnt[v.x & (VOCAB - 1)], 1u);
            atomicAdd(&sm.cnt[v.y & (VOCAB - 1)], 1u);
            atomicAdd(&sm.cnt[v.z & (VOCAB - 1)], 1u);
            atomicAdd(&sm.cnt[v.w & (VOCAB - 1)], 1u);
        }
        __syncthreads();

        unsigned* __restrict__ row = counts + ((size_t)b * HSEG + seg) * VOCAB;
#pragma unroll
        for (int i = 0; i < 4; ++i) st_u32(&row[tid * 4 + i], sm.cnt[tid * 4 + i]);
        signal(&flagH[b]);
    }

    // ===== Phase 2: dense1 (1024->512, relu); pooled fused from counts =====
    {
        const int rg = blk >> 4;  // 16 rowgroups
        const int jw = blk & 15;  // 16 j-windows
        const int b0 = rg * 4;
        if (tid == 0) {
#pragma unroll
            for (int r = 0; r < 4; ++r)
                while (__hip_atomic_load(&flagH[b0 + r].v, __ATOMIC_RELAXED, AGENT) != HSEG)
                    __builtin_amdgcn_s_sleep(1);
        }
        __syncthreads();

        // stage pooled (counts segsum / T) transposed into LDS (plain loads)
        {
            const float invT = 1.0f / (float)TOK_T;
#pragma unroll
            for (int ko = 0; ko < 4; ++ko) {
                const int k = tid + 256 * ko;
                float4 v;
#pragma unroll
                for (int r = 0; r < 4; ++r) {
                    const unsigned* __restrict__ cr = counts + (size_t)(b0 + r) * HSEG * VOCAB;
                    unsigned s = cr[k] + cr[k + VOCAB] + cr[k + 2 * VOCAB] + cr[k + 3 * VOCAB];
                    (&v.x)[r] = (float)s * invT;
                }
                sm.d.xs4[XSIDX(k)] = v;
            }
        }
        __syncthreads();

        constexpr int K = VOCAB, OUT = HIDDEN, KG = 16, KC = K / KG;
        const int jt = tid & 15;
        const int kg = tid >> 4;
        const float* __restrict__ w = W1 + (size_t)(kg * KC) * OUT + jw * 32 + jt * 2;
        float2 acc0 = {0.f, 0.f}, acc1 = {0.f, 0.f}, acc2 = {0.f, 0.f}, acc3 = {0.f, 0.f};
#pragma unroll 8
        for (int ks = 0; ks < KC; ++ks) {
            const int k = kg * KC + ks;
            const float4 xv = sm.d.xs4[XSIDX(k)];
            const float2 wv = *(const float2*)(w + (size_t)ks * OUT);
            acc0.x = fmaf(xv.x, wv.x, acc0.x); acc0.y = fmaf(xv.x, wv.y, acc0.y);
            acc1.x = fmaf(xv.y, wv.x, acc1.x); acc1.y = fmaf(xv.y, wv.y, acc1.y);
            acc2.x = fmaf(xv.z, wv.x, acc2.x); acc2.y = fmaf(xv.z, wv.y, acc2.y);
            acc3.x = fmaf(xv.w, wv.x, acc3.x); acc3.y = fmaf(xv.w, wv.y, acc3.y);
        }
        *(float2*)&sm.d.part[kg][0][jt * 2] = acc0;
        *(float2*)&sm.d.part[kg][1][jt * 2] = acc1;
        *(float2*)&sm.d.part[kg][2][jt * 2] = acc2;
        *(float2*)&sm.d.part[kg][3][jt * 2] = acc3;
        __syncthreads();
        if (tid < 128) {
            const int r = tid >> 5;
            const int jl = tid & 31;
            float s = b1[jw * 32 + jl];
#pragma unroll
            for (int g = 0; g < KG; ++g) s += sm.d.part[g][r][jl];
            st_f32(&h1[(size_t)(b0 + r) * OUT + jw * 32 + jl], fmaxf(s, 0.0f));
        }
        signal(&flag1[rg]);
    }

    // ===== Phase 3: dense2 (512->512, relu) =====
    {
        const int rg = blk >> 4;
        const int jw = blk & 15;
        wait_flag(&flag1[rg], 16);
        dense_phase<HIDDEN, HIDDEN, true, false>(sm, rg, jw, h1, W2, b2, h2, nullptr);
        signal(&flag2[rg]);
    }

    // ===== Phase 4: dense3 (512->256) + ssq partials (blocks 0-127) =====
    if (blk < (BATCH / 4) * (EMBED / 32)) {
        const int rg = blk >> 3;  // 16 rowgroups
        const int jw = blk & 7;   // 8 j-windows
        wait_flag(&flag2[rg], 16);
        dense_phase<HIDDEN, EMBED, false, true>(sm, rg, jw, h2, W3, b3, emb, ssqp);
        signal(&flag3[rg]);
    }

    // ===== Phase 5: L2 normalize (blocks 0-63, one row each) =====
    if (blk < BATCH) {
        const int b = blk;
        wait_flag(&flag3[b >> 2], 8);
        float total = 0.0f;
#pragma unroll
        for (int i = 0; i < EMBED / 32; ++i) total += ssqp[(size_t)b * (EMBED / 32) + i];
        const float v = emb[(size_t)b * EMBED + tid];
        out[(size_t)b * EMBED + tid] = v / fmaxf(sqrtf(total), 1e-12f);  // F.normalize eps
    }
}

// ---------------------------------------------------------------------------
// Launch: 14-KB flag-clear memset + ONE regular kernel launch.
// ---------------------------------------------------------------------------
extern "C" void kernel_launch(void* const* d_in, const int* in_sizes, int n_in,
                              void* d_out, int out_size, void* d_ws, size_t ws_size,
                              hipStream_t stream) {
    const int*   tokens = (const int*)d_in[0];   // [64,16384], values in [0,1024)
    const float* W1     = (const float*)d_in[1]; // [1024,512]
    const float* b1     = (const float*)d_in[2]; // [512]
    const float* W2     = (const float*)d_in[3]; // [512,512]
    const float* b2     = (const float*)d_in[4]; // [512]
    const float* W3     = (const float*)d_in[5]; // [512,256]
    const float* b3     = (const float*)d_in[6]; // [256]
    float*       out    = (float*)d_out;         // [64,256]

    // Workspace layout (byte offsets; all regions fully rewritten every call).
    uint8_t* base = (uint8_t*)d_ws;
    unsigned* counts = (unsigned*)(base);             // [64][4][1024] u32 = 1 MB
    float*    h1     = (float*)(base + 0x100000);     // [64][512] = 128 KB
    float*    h2     = (float*)(base + 0x120000);     // [64][512] = 128 KB
    float*    emb    = (float*)(base + 0x140000);     // [64][256] = 64 KB
    float*    ssqp   = (float*)(base + 0x150000);     // [64][8]   = 2 KB
    Flag*     flagH  = (Flag*)(base + 0x150800);      // 64 x 128 B
    Flag*     flag1  = flagH + BATCH;                 // 16 x 128 B
    Flag*     flag2  = flag1 + 16;                    // 16 x 128 B
    Flag*     flag3  = flag2 + 16;                    // 16 x 128 B

    // Flags must start at 0 every call: 112 x 128 B = 14336 B.
    hipMemsetAsync((void*)flagH, 0, 112 * sizeof(Flag), stream);

    fused_kernel<<<256, 256, 0, stream>>>(tokens, W1, b1, W2, b2, W3, b3, out,
                                          counts, h1, h2, emb, ssqp,
                                          flagH, flag1, flag2, flag3);
}